// Round 13
// baseline (97.954 us; speedup 1.0000x reference)
//
#include <hip/hip_runtime.h>
#include <cstdint>

#define BB 256
#define NN 128
#define DD 512
#define HH 512

typedef __attribute__((ext_vector_type(8))) short bf16x8;
typedef __attribute__((ext_vector_type(16))) float f32x16;
typedef unsigned short u16;

static __device__ __forceinline__ u16 f2bf(float f) {
    union { float f; uint32_t u; } v; v.f = f;
    uint32_t u = v.u;
    return (u16)((u + 0x7FFFu + ((u >> 16) & 1u)) >> 16);
}

static __device__ __forceinline__ void gload16(const u16* g, u16* l) {
    __builtin_amdgcn_global_load_lds((const __attribute__((address_space(1))) void*)g,
                                     (__attribute__((address_space(3))) void*)l, 16, 0, 0);
}

// ---------------- W fp32 -> bf16 (once) ----------------
__global__ __launch_bounds__(256) void wconv_kernel(const float* __restrict__ W, u16* __restrict__ Wb) {
    int idx = (blockIdx.x * 256 + threadIdx.x) * 4;
    float4 v = *(const float4*)(W + idx);
    ushort4 o;
    o.x = f2bf(v.x); o.y = f2bf(v.y); o.z = f2bf(v.z); o.w = f2bf(v.w);
    *(ushort4*)(Wb + idx) = o;
}

// ---------------- Yt[b][h][m] = sum_d X[b][m][d] * W[h][d]  (flat GEMM) ----------------
// grid 512 = 128 m-tiles (256 flat rows = 2 batches) x 4 h-tiles (128 h).
// 512 thr = 8 waves: hq = w&3 -> 32-h strip (A = W rows), mh = w>>2 -> 128-m half (B = X cols).
// LDS 48K (Xs 2x16K + Ws 2x8K) -> 2 blocks/CU; acc[4] = 64 VGPR within the 128 cap.
// W traffic: 512 blocks x 128h x 1KB = 64 MB (vs 256 MB in the per-batch form).
__global__ __launch_bounds__(512, 2) void yt_kernel(const float* __restrict__ X, const u16* __restrict__ Wb,
                                                    u16* __restrict__ Yt) {
    __shared__ __align__(16) char smem[49152];  // Xs[buf][256 m][32 k] @0; Ws[buf][128 h][32 k] @32768

    const int t = threadIdx.x;
    const int lane = t & 63, w = t >> 6, l31 = lane & 31, lh = lane >> 5;
    const int mblk = (int)blockIdx.x >> 2, hblk = (int)blockIdx.x & 3;
    const int m0 = mblk * 256, h0 = hblk * 128;
    const int hq = w & 3, mh = w >> 2;

    float4 xr[4];

#define XLOAD(KS)                                                                         \
    {                                                                                     \
        const int k0_ = (KS) * 32;                                                        \
        _Pragma("unroll")                                                                 \
        for (int it_ = 0; it_ < 4; ++it_) {                                               \
            int q_ = it_ * 512 + t;                                                       \
            int m_ = q_ >> 3, c4_ = q_ & 7;                                               \
            xr[it_] = *(const float4*)(X + (size_t)(m0 + m_) * DD + k0_ + c4_ * 4);       \
        }                                                                                 \
    }

#define XWRITE(BUF)                                                                       \
    {                                                                                     \
        char* xb_ = smem + (BUF) * 16384;                                                 \
        _Pragma("unroll")                                                                 \
        for (int it_ = 0; it_ < 4; ++it_) {                                               \
            int q_ = it_ * 512 + t;                                                       \
            int m_ = q_ >> 3, c4_ = q_ & 7;                                               \
            ushort4 o_;                                                                   \
            o_.x = f2bf(xr[it_].x); o_.y = f2bf(xr[it_].y);                               \
            o_.z = f2bf(xr[it_].z); o_.w = f2bf(xr[it_].w);                               \
            *(ushort4*)(xb_ + m_ * 64 + (((c4_ >> 1) ^ (m_ & 3)) << 4) + ((c4_ & 1) << 3)) = o_; \
        }                                                                                 \
    }

#define WGLOAD(KS, BUF)                                                                   \
    {                                                                                     \
        u16* wd_ = (u16*)(smem + 32768 + (BUF) * 8192);                                   \
        int h_ = t >> 2, c_ = t & 3;                                                      \
        gload16(Wb + (size_t)(h0 + h_) * DD + (KS) * 32 + ((c_ ^ (h_ & 3)) * 8),          \
                wd_ + t * 8);                                                             \
    }

    f32x16 acc[4];
    #pragma unroll
    for (int mf = 0; mf < 4; ++mf)
        #pragma unroll
        for (int r = 0; r < 16; ++r)
            acc[mf][r] = 0.f;

    XLOAD(0);
    WGLOAD(0, 0);
    XWRITE(0);
    __syncthreads();

    for (int ks = 0; ks < 16; ++ks) {
        const int buf = ks & 1;
        if (ks < 15) {
            XLOAD(ks + 1);
            WGLOAD(ks + 1, buf ^ 1);
        }
        const u16* xs = (const u16*)(smem + buf * 16384);
        const u16* ws = (const u16*)(smem + 32768 + buf * 8192);
        #pragma unroll
        for (int s2 = 0; s2 < 2; ++s2) {
            const int kc = s2 * 2 + lh;
            const int h = hq * 32 + l31;
            bf16x8 af = *(const bf16x8*)(ws + h * 32 + ((kc ^ (h & 3)) << 3));
            bf16x8 bx[4];
            #pragma unroll
            for (int mf = 0; mf < 4; ++mf) {
                int m = mh * 128 + mf * 32 + l31;
                bx[mf] = *(const bf16x8*)(xs + m * 32 + ((kc ^ (m & 3)) << 3));
            }
            #pragma unroll
            for (int mf = 0; mf < 4; ++mf)
                acc[mf] = __builtin_amdgcn_mfma_f32_32x32x16_bf16(af, bx[mf], acc[mf], 0, 0, 0);
        }
        __syncthreads();          // MFMA reads done; next-step gloads landed
        if (ks < 15) XWRITE(buf ^ 1);
        __syncthreads();          // X writes visible
    }
#undef XLOAD
#undef XWRITE
#undef WGLOAD

    // store Y^T per batch: D rows = h, cols = m (lane l31 = m -> coalesced)
    #pragma unroll
    for (int mf = 0; mf < 4; ++mf) {
        int gm = m0 + mh * 128 + mf * 32 + l31;
        int bt = gm >> 7, mloc = gm & 127;
        u16* base = Yt + (size_t)bt * (HH * NN) + (size_t)h0 * NN + mloc;
        #pragma unroll
        for (int r = 0; r < 16; ++r) {
            int h = hq * 32 + (r & 3) + 8 * (r >> 2) + 4 * lh;
            base[(size_t)h * NN] = f2bf(acc[mf][r]);
        }
    }
}

// ---------------- out = sigmoid(LN( (I + A_norm) @ Y + bias )) ----------------
// 1 block/batch (256 blocks = 1/CU). LDS: Ms[128][128] 32K + Yt[512 h][128 m] 128K = 160K,
// both fully resident -> ZERO barriers in the GEMM. LN in 4 i-passes of 32 rows;
// stats overlay the just-dead Ms quarter. acc[2]=32 + stats 32 regs -> no spill.
__global__ __launch_bounds__(512) void aggln_kernel(const float* __restrict__ A, const u16* __restrict__ Yt,
                                                    const float* __restrict__ bias, const float* __restrict__ lnw,
                                                    const float* __restrict__ lnb, float* __restrict__ out) {
    __shared__ __align__(16) char smem[163840];
    u16* Ms = (u16*)smem;                 // [128 i][128 m], chunk c' = c ^ (i&15)
    u16* Yl = (u16*)(smem + 32768);       // [512 h][128 m], chunk c' = c ^ (h&7)

    const int t = threadIdx.x;
    const int lane = t & 63, w = t >> 6, l31 = lane & 31, lh = lane >> 5;
    const int batch = blockIdx.x;

    // A row loads first (latency overlaps Yt gload issue)
    const int row = t >> 2, seg = t & 3;
    const float* Ag = A + (size_t)batch * NN * NN + row * NN + seg * 32;
    float4 a[8];
    #pragma unroll
    for (int j = 0; j < 8; ++j) a[j] = *(const float4*)(Ag + j * 4);

    // stage Yt[b] via gload16, source chunk-swizzled (involution c ^= h&7)
    {
        const u16* Ytg = Yt + (size_t)batch * (HH * NN);
        #pragma unroll
        for (int it = 0; it < 16; ++it) {
            int q = it * 512 + t;
            int h = q >> 4, c = q & 15;
            gload16(Ytg + (size_t)h * NN + ((c ^ (h & 7)) * 8), Yl + q * 8);
        }
    }

    // build M = A_norm + I
    {
        float s = 0.f;
        #pragma unroll
        for (int j = 0; j < 8; ++j) s += a[j].x + a[j].y + a[j].z + a[j].w;
        s += __shfl_xor(s, 1);
        s += __shfl_xor(s, 2);
        const float inv = 1.0f / (s + 1e-6f);
        #pragma unroll
        for (int c2 = 0; c2 < 4; ++c2) {
            u16 tmp[8];
            const float* pe = (const float*)&a[c2 * 2];
            #pragma unroll
            for (int e = 0; e < 8; ++e) {
                int m = seg * 32 + c2 * 8 + e;
                tmp[e] = f2bf(pe[e] * inv + (m == row ? 1.0f : 0.0f));
            }
            int c = seg * 4 + c2;
            *(uint4*)(Ms + row * 128 + ((c ^ (row & 15)) << 3)) = *(const uint4*)tmp;
        }
    }
    __syncthreads();   // Ms visible, Yt gloads drained

    float bias_v[2], lnw_v[2], lnb_v[2];
    #pragma unroll
    for (int fh = 0; fh < 2; ++fh) {
        int h = w * 64 + fh * 32 + l31;
        bias_v[fh] = bias[h];
        lnw_v[fh] = lnw[h];
        lnb_v[fh] = lnb[h];
    }
    float* Og = out + (size_t)batch * NN * HH;

    #pragma unroll
    for (int ih = 0; ih < 4; ++ih) {
        f32x16 acc[2];
        #pragma unroll
        for (int fh = 0; fh < 2; ++fh)
            #pragma unroll
            for (int r = 0; r < 16; ++r)
                acc[fh][r] = 0.f;

        #pragma unroll
        for (int s8 = 0; s8 < 8; ++s8) {
            const int kc = s8 * 2 + lh;
            const int i = ih * 32 + l31;
            bf16x8 af = *(const bf16x8*)(Ms + i * 128 + ((kc ^ (i & 15)) << 3));
            bf16x8 bw[2];
            #pragma unroll
            for (int fh = 0; fh < 2; ++fh) {
                int h = w * 64 + fh * 32 + l31;
                bw[fh] = *(const bf16x8*)(Yl + h * 128 + ((kc ^ (h & 7)) << 3));
            }
            #pragma unroll
            for (int fh = 0; fh < 2; ++fh)
                acc[fh] = __builtin_amdgcn_mfma_f32_32x32x16_bf16(af, bw[fh], acc[fh], 0, 0, 0);
        }
        __syncthreads();   // all waves done reading Ms quarter ih -> overlay it

        float* Pss = (float*)(smem + ih * 8192);          // [8 w][32 rl][2]
        float* musig = (float*)(smem + ih * 8192 + 4096); // [32 rl][2]

        float rs[16], rss[16];
        #pragma unroll
        for (int r = 0; r < 16; ++r) {
            float a0 = acc[0][r] + bias_v[0];
            float a1 = acc[1][r] + bias_v[1];
            acc[0][r] = a0; acc[1][r] = a1;
            rs[r] = a0 + a1;
            rss[r] = a0 * a0 + a1 * a1;
        }
        #pragma unroll
        for (int msk = 1; msk <= 16; msk <<= 1)
            #pragma unroll
            for (int r = 0; r < 16; ++r) {
                rs[r] += __shfl_xor(rs[r], msk);
                rss[r] += __shfl_xor(rss[r], msk);
            }
        if (l31 == 0) {
            #pragma unroll
            for (int r = 0; r < 16; ++r) {
                int rl = (r & 3) + 8 * (r >> 2) + 4 * lh;
                float2 v; v.x = rs[r]; v.y = rss[r];
                *(float2*)(Pss + (w * 32 + rl) * 2) = v;
            }
        }
        __syncthreads();
        if (t < 32) {
            float s = 0.f, ss = 0.f;
            #pragma unroll
            for (int q = 0; q < 8; ++q) {
                float2 v = *(const float2*)(Pss + (q * 32 + t) * 2);
                s += v.x; ss += v.y;
            }
            float mean = s * (1.0f / 512.0f);
            float var = ss * (1.0f / 512.0f) - mean * mean;
            float2 mz; mz.x = mean; mz.y = rsqrtf(var + 1e-5f);
            *(float2*)(musig + t * 2) = mz;
        }
        __syncthreads();

        #pragma unroll
        for (int r = 0; r < 16; ++r) {
            int rl = (r & 3) + 8 * (r >> 2) + 4 * lh;
            float2 mz = *(const float2*)(musig + rl * 2);
            #pragma unroll
            for (int fh = 0; fh < 2; ++fh) {
                float xn = (acc[fh][r] - mz.x) * mz.y * lnw_v[fh] + lnb_v[fh];
                Og[(size_t)(ih * 32 + rl) * HH + w * 64 + fh * 32 + l31] =
                    1.0f / (1.0f + __expf(-xn));
            }
        }
    }
}

extern "C" void kernel_launch(void* const* d_in, const int* in_sizes, int n_in,
                              void* d_out, int out_size, void* d_ws, size_t ws_size,
                              hipStream_t stream) {
    const float* X = (const float*)d_in[0];
    const float* A = (const float*)d_in[1];
    const float* W = (const float*)d_in[2];
    const float* bias = (const float*)d_in[3];
    const float* lnw = (const float*)d_in[4];
    const float* lnb = (const float*)d_in[5];
    float* out = (float*)d_out;

    u16* Yt = (u16*)d_ws;                                  // B*H*N bf16 = 32 MB
    u16* Wb = (u16*)d_ws + (size_t)BB * HH * NN;           // H*D bf16 = 512 KB

    hipLaunchKernelGGL(wconv_kernel, dim3(256), dim3(256), 0, stream, W, Wb);
    hipLaunchKernelGGL(yt_kernel, dim3(512), dim3(512), 0, stream, X, Wb, Yt);
    hipLaunchKernelGGL(aggln_kernel, dim3(256), dim3(512), 0, stream, A, Yt, bias, lnw, lnb, out);
}

// Round 15
// 92.302 us; speedup vs baseline: 1.0612x; 1.0612x over previous
//
#include <hip/hip_runtime.h>
#include <cstdint>

#define BB 256
#define NN 128
#define DD 512
#define HH 512

typedef __attribute__((ext_vector_type(8))) short bf16x8;
typedef __attribute__((ext_vector_type(16))) float f32x16;
typedef unsigned short u16;

static __device__ __forceinline__ u16 f2bf(float f) {
    union { float f; uint32_t u; } v; v.f = f;
    uint32_t u = v.u;
    return (u16)((u + 0x7FFFu + ((u >> 16) & 1u)) >> 16);
}

static __device__ __forceinline__ void gload16(const u16* g, u16* l) {
    __builtin_amdgcn_global_load_lds((const __attribute__((address_space(1))) void*)g,
                                     (__attribute__((address_space(3))) void*)l, 16, 0, 0);
}

// ---------------- W fp32 -> bf16 (once) ----------------
__global__ __launch_bounds__(256) void wconv_kernel(const float* __restrict__ W, u16* __restrict__ Wb) {
    int idx = (blockIdx.x * 256 + threadIdx.x) * 4;
    float4 v = *(const float4*)(W + idx);
    ushort4 o;
    o.x = f2bf(v.x); o.y = f2bf(v.y); o.z = f2bf(v.z); o.w = f2bf(v.w);
    *(ushort4*)(Wb + idx) = o;
}

// ---------------- Xagg = (I + A_norm) @ X -> HBM bf16  (R12-verified, replay-safe) ----------------
__global__ __launch_bounds__(512) void agg_kernel(const float* __restrict__ X, const float* __restrict__ A,
                                                  u16* __restrict__ Xagg) {
    __shared__ __align__(16) char smem[163840];
    u16* Ms = (u16*)smem;                 // [128 i][128 m], chunk c' = c ^ (i&15)
    u16* Xt = (u16*)(smem + 32768);       // [512 d][128 m], chunk c' = c ^ ((d>>2)&7)

    const int t = threadIdx.x;
    const int lane = t & 63, w = t >> 6, l31 = lane & 31, lh = lane >> 5;
    const int batch = blockIdx.x;
    const int wm = w >> 2, wn = w & 3;

    {
        const int row = t >> 2, seg = t & 3;
        const float* Ag = A + (size_t)batch * NN * NN + row * NN + seg * 32;
        float4 a[8];
        #pragma unroll
        for (int j = 0; j < 8; ++j) a[j] = *(const float4*)(Ag + j * 4);
        float s = 0.f;
        #pragma unroll
        for (int j = 0; j < 8; ++j) s += a[j].x + a[j].y + a[j].z + a[j].w;
        s += __shfl_xor(s, 1);
        s += __shfl_xor(s, 2);
        const float inv = 1.0f / (s + 1e-6f);
        #pragma unroll
        for (int c2 = 0; c2 < 4; ++c2) {
            u16 tmp[8];
            const float* pe = (const float*)&a[c2 * 2];
            #pragma unroll
            for (int e = 0; e < 8; ++e) {
                int m = seg * 32 + c2 * 8 + e;
                tmp[e] = f2bf(pe[e] * inv + (m == row ? 1.0f : 0.0f));
            }
            int c = seg * 4 + c2;
            *(uint4*)(Ms + row * 128 + ((c ^ (row & 15)) << 3)) = *(const uint4*)tmp;
        }
    }

    {
        const float* Xg = X + (size_t)batch * NN * DD;
        #pragma unroll
        for (int it = 0; it < 32; ++it) {
            int q = it * 512 + t;
            int m = q >> 7, c4 = q & 127;
            float4 v = *(const float4*)(Xg + (size_t)m * DD + c4 * 4);
            float fv[4] = {v.x, v.y, v.z, v.w};
            #pragma unroll
            for (int j = 0; j < 4; ++j) {
                int d = c4 * 4 + j;
                Xt[d * 128 + (((m >> 3) ^ ((d >> 2) & 7)) << 3) + (m & 7)] = f2bf(fv[j]);
            }
        }
    }
    __syncthreads();

    u16* Og = Xagg + (size_t)batch * NN * DD;
    #pragma unroll
    for (int dh = 0; dh < 2; ++dh) {
        f32x16 acc1[2][2];
        #pragma unroll
        for (int fi = 0; fi < 2; ++fi)
            #pragma unroll
            for (int fd = 0; fd < 2; ++fd)
                #pragma unroll
                for (int r = 0; r < 16; ++r)
                    acc1[fi][fd][r] = 0.f;

        #pragma unroll
        for (int ksl = 0; ksl < 8; ++ksl) {
            const int kc = ksl * 2 + lh;
            bf16x8 af[2], bx[2];
            #pragma unroll
            for (int fi = 0; fi < 2; ++fi) {
                int i = wm * 64 + fi * 32 + l31;
                af[fi] = *(const bf16x8*)(Ms + i * 128 + ((kc ^ (i & 15)) << 3));
            }
            #pragma unroll
            for (int fd = 0; fd < 2; ++fd) {
                int d = dh * 256 + wn * 64 + fd * 32 + l31;
                bx[fd] = *(const bf16x8*)(Xt + d * 128 + ((kc ^ ((d >> 2) & 7)) << 3));
            }
            #pragma unroll
            for (int fi = 0; fi < 2; ++fi)
                #pragma unroll
                for (int fd = 0; fd < 2; ++fd)
                    acc1[fi][fd] = __builtin_amdgcn_mfma_f32_32x32x16_bf16(af[fi], bx[fd], acc1[fi][fd], 0, 0, 0);
        }

        #pragma unroll
        for (int fi = 0; fi < 2; ++fi)
            #pragma unroll
            for (int r = 0; r < 16; ++r) {
                int i = wm * 64 + fi * 32 + (r & 3) + 8 * (r >> 2) + 4 * lh;
                #pragma unroll
                for (int fd = 0; fd < 2; ++fd) {
                    int d = dh * 256 + wn * 64 + fd * 32 + l31;
                    Og[(size_t)i * DD + d] = f2bf(acc1[fi][fd][r]);
                }
            }
    }
}

// ---------------- out = sigmoid(LN( Xagg @ W^T + bias )) ----------------
// grid 512 (M-tile 64), 256 thr = 4 waves; wave w -> h strip [128w, 128w+128).
// 2 blocks/CU at 2 waves/SIMD (launch_bounds (256,2) -> 256-VGPR budget; acc[2][4]=128 regs).
// K-loop: T3-minimum 2-phase — STAGE(next) issued BEFORE compute(cur), ONE
// __syncthreads() per step (full drain; replay-safe — R14's counted-vmcnt raced on replay).
__global__ __launch_bounds__(256, 2) void gemm_ln_kernel(const u16* __restrict__ Xagg, const u16* __restrict__ Wb,
                                                         const float* __restrict__ bias, const float* __restrict__ lnw,
                                                         const float* __restrict__ lnb, float* __restrict__ out) {
    __shared__ __align__(16) char smem[73728];   // W slabs 2x32K @0; Xa slabs 2x4K @65536
    float* Pss = (float*)smem;                   // overlay after K-loop: [4 w][64 row][2]
    float* musig = (float*)(smem + 2048);        // [64 row][2]

    const int t = threadIdx.x;
    const int lane = t & 63, w = t >> 6, l31 = lane & 31, lh = lane >> 5;
    const size_t rb = (size_t)blockIdx.x * 64;
    const u16* Xab = Xagg + rb * DD;

    float bias_v[4], lnw_v[4], lnb_v[4];
    #pragma unroll
    for (int fh = 0; fh < 4; ++fh) {
        int h = w * 128 + fh * 32 + l31;
        bias_v[fh] = bias[h];
        lnw_v[fh] = lnw[h];
        lnb_v[fh] = lnb[h];
    }

#define STAGE(KS, BUF)                                                               \
    {                                                                                \
        const int k0_ = (KS) * 32;                                                   \
        u16* wl_ = (u16*)(smem + (BUF) * 32768);                                     \
        u16* xal_ = (u16*)(smem + 65536 + (BUF) * 4096);                             \
        _Pragma("unroll")                                                            \
        for (int it_ = 0; it_ < 8; ++it_) {                                          \
            int q_ = it_ * 256 + t;                                                  \
            int h_ = q_ >> 2, cc_ = q_ & 3;                                          \
            gload16(Wb + (size_t)h_ * DD + k0_ + ((cc_ ^ ((h_ >> 1) & 3)) * 8),      \
                    wl_ + q_ * 8);                                                   \
        }                                                                            \
        {                                                                            \
            int m_ = t >> 2, cc_ = t & 3;                                            \
            gload16(Xab + (size_t)m_ * DD + k0_ + ((cc_ ^ ((m_ >> 1) & 3)) * 8),     \
                    xal_ + t * 8);                                                   \
        }                                                                            \
    }

    f32x16 acc[2][4];
    #pragma unroll
    for (int mi = 0; mi < 2; ++mi)
        #pragma unroll
        for (int fh = 0; fh < 4; ++fh)
            #pragma unroll
            for (int r = 0; r < 16; ++r)
                acc[mi][fh][r] = 0.f;

    STAGE(0, 0);
    __syncthreads();
    for (int ks = 0; ks < 16; ++ks) {
        const int buf = ks & 1;
        if (ks < 15) STAGE(ks + 1, buf ^ 1);   // issue-early: latency hides under compute

        const u16* wl = (const u16*)(smem + buf * 32768);
        const u16* xal = (const u16*)(smem + 65536 + buf * 4096);
        #pragma unroll
        for (int s2 = 0; s2 < 2; ++s2) {
            const int kc = s2 * 2 + lh;
            bf16x8 af[2], bw[4];
            #pragma unroll
            for (int mi = 0; mi < 2; ++mi) {
                int m = mi * 32 + l31;
                af[mi] = *(const bf16x8*)(xal + (m * 4 + (kc ^ ((m >> 1) & 3))) * 8);
            }
            #pragma unroll
            for (int fh = 0; fh < 4; ++fh) {
                int h = w * 128 + fh * 32 + l31;
                bw[fh] = *(const bf16x8*)(wl + (h * 4 + (kc ^ ((h >> 1) & 3))) * 8);
            }
            #pragma unroll
            for (int mi = 0; mi < 2; ++mi)
                #pragma unroll
                for (int fh = 0; fh < 4; ++fh)
                    acc[mi][fh] = __builtin_amdgcn_mfma_f32_32x32x16_bf16(af[mi], bw[fh], acc[mi][fh], 0, 0, 0);
        }
        __syncthreads();   // drains next-buf gloads + this-buf reads; one barrier per step
    }
#undef STAGE

    // bias + per-row stats over this wave's 128 h
    float rs[2][16], rss[2][16];
    #pragma unroll
    for (int mi = 0; mi < 2; ++mi)
        #pragma unroll
        for (int r = 0; r < 16; ++r) {
            float s = 0.f, ss = 0.f;
            #pragma unroll
            for (int fh = 0; fh < 4; ++fh) {
                float a = acc[mi][fh][r] + bias_v[fh];
                acc[mi][fh][r] = a;
                s += a; ss += a * a;
            }
            rs[mi][r] = s; rss[mi][r] = ss;
        }
    #pragma unroll
    for (int msk = 1; msk <= 16; msk <<= 1)
        #pragma unroll
        for (int mi = 0; mi < 2; ++mi)
            #pragma unroll
            for (int r = 0; r < 16; ++r) {
                rs[mi][r] += __shfl_xor(rs[mi][r], msk);
                rss[mi][r] += __shfl_xor(rss[mi][r], msk);
            }
    if (l31 == 0) {
        #pragma unroll
        for (int mi = 0; mi < 2; ++mi)
            #pragma unroll
            for (int r = 0; r < 16; ++r) {
                int rl = mi * 32 + (r & 3) + 8 * (r >> 2) + 4 * lh;
                float2 v; v.x = rs[mi][r]; v.y = rss[mi][r];
                *(float2*)(Pss + (w * 64 + rl) * 2) = v;
            }
    }
    __syncthreads();
    if (t < 64) {
        float s = 0.f, ss = 0.f;
        #pragma unroll
        for (int q = 0; q < 4; ++q) {
            float2 v = *(const float2*)(Pss + (q * 64 + t) * 2);
            s += v.x; ss += v.y;
        }
        float mean = s * (1.0f / 512.0f);
        float var = ss * (1.0f / 512.0f) - mean * mean;
        float2 mz; mz.x = mean; mz.y = rsqrtf(var + 1e-5f);
        *(float2*)(musig + t * 2) = mz;
    }
    __syncthreads();

    #pragma unroll
    for (int mi = 0; mi < 2; ++mi)
        #pragma unroll
        for (int r = 0; r < 16; ++r) {
            int rl = mi * 32 + (r & 3) + 8 * (r >> 2) + 4 * lh;
            float2 mz = *(const float2*)(musig + rl * 2);
            #pragma unroll
            for (int fh = 0; fh < 4; ++fh) {
                float xn = (acc[mi][fh][r] - mz.x) * mz.y * lnw_v[fh] + lnb_v[fh];
                out[(rb + rl) * HH + w * 128 + fh * 32 + l31] = 1.0f / (1.0f + __expf(-xn));
            }
        }
}

extern "C" void kernel_launch(void* const* d_in, const int* in_sizes, int n_in,
                              void* d_out, int out_size, void* d_ws, size_t ws_size,
                              hipStream_t stream) {
    const float* X = (const float*)d_in[0];
    const float* A = (const float*)d_in[1];
    const float* W = (const float*)d_in[2];
    const float* bias = (const float*)d_in[3];
    const float* lnw = (const float*)d_in[4];
    const float* lnb = (const float*)d_in[5];
    float* out = (float*)d_out;

    u16* Xagg = (u16*)d_ws;                                  // B*N*D bf16 = 32 MB
    u16* Wb = (u16*)d_ws + (size_t)BB * NN * DD;             // H*D bf16 = 512 KB

    hipLaunchKernelGGL(wconv_kernel, dim3(256), dim3(256), 0, stream, W, Wb);
    hipLaunchKernelGGL(agg_kernel, dim3(256), dim3(512), 0, stream, X, A, Xagg);
    hipLaunchKernelGGL(gemm_ln_kernel, dim3(512), dim3(256), 0, stream, Xagg, Wb, bias, lnw, lnb, out);
}

// Round 16
// 88.164 us; speedup vs baseline: 1.1110x; 1.0469x over previous
//
#include <hip/hip_runtime.h>
#include <cstdint>

#define BB 256
#define NN 128
#define DD 512
#define HH 512

typedef __attribute__((ext_vector_type(8))) short bf16x8;
typedef __attribute__((ext_vector_type(16))) float f32x16;
typedef unsigned short u16;

static __device__ __forceinline__ u16 f2bf(float f) {
    union { float f; uint32_t u; } v; v.f = f;
    uint32_t u = v.u;
    return (u16)((u + 0x7FFFu + ((u >> 16) & 1u)) >> 16);
}

static __device__ __forceinline__ void gload16(const u16* g, u16* l) {
    __builtin_amdgcn_global_load_lds((const __attribute__((address_space(1))) void*)g,
                                     (__attribute__((address_space(3))) void*)l, 16, 0, 0);
}

// ---------------- W fp32 -> bf16 (once) ----------------
__global__ __launch_bounds__(256) void wconv_kernel(const float* __restrict__ W, u16* __restrict__ Wb) {
    int idx = (blockIdx.x * 256 + threadIdx.x) * 4;
    float4 v = *(const float4*)(W + idx);
    ushort4 o;
    o.x = f2bf(v.x); o.y = f2bf(v.y); o.z = f2bf(v.z); o.w = f2bf(v.w);
    *(ushort4*)(Wb + idx) = o;
}

// ---------------- Xagg = (I + A_norm) @ X -> HBM bf16  (R12-verified) ----------------
__global__ __launch_bounds__(512) void agg_kernel(const float* __restrict__ X, const float* __restrict__ A,
                                                  u16* __restrict__ Xagg) {
    __shared__ __align__(16) char smem[163840];
    u16* Ms = (u16*)smem;                 // [128 i][128 m], chunk c' = c ^ (i&15)
    u16* Xt = (u16*)(smem + 32768);       // [512 d][128 m], chunk c' = c ^ ((d>>2)&7)

    const int t = threadIdx.x;
    const int lane = t & 63, w = t >> 6, l31 = lane & 31, lh = lane >> 5;
    const int batch = blockIdx.x;
    const int wm = w >> 2, wn = w & 3;

    {
        const int row = t >> 2, seg = t & 3;
        const float* Ag = A + (size_t)batch * NN * NN + row * NN + seg * 32;
        float4 a[8];
        #pragma unroll
        for (int j = 0; j < 8; ++j) a[j] = *(const float4*)(Ag + j * 4);
        float s = 0.f;
        #pragma unroll
        for (int j = 0; j < 8; ++j) s += a[j].x + a[j].y + a[j].z + a[j].w;
        s += __shfl_xor(s, 1);
        s += __shfl_xor(s, 2);
        const float inv = 1.0f / (s + 1e-6f);
        #pragma unroll
        for (int c2 = 0; c2 < 4; ++c2) {
            u16 tmp[8];
            const float* pe = (const float*)&a[c2 * 2];
            #pragma unroll
            for (int e = 0; e < 8; ++e) {
                int m = seg * 32 + c2 * 8 + e;
                tmp[e] = f2bf(pe[e] * inv + (m == row ? 1.0f : 0.0f));
            }
            int c = seg * 4 + c2;
            *(uint4*)(Ms + row * 128 + ((c ^ (row & 15)) << 3)) = *(const uint4*)tmp;
        }
    }

    {
        const float* Xg = X + (size_t)batch * NN * DD;
        #pragma unroll
        for (int it = 0; it < 32; ++it) {
            int q = it * 512 + t;
            int m = q >> 7, c4 = q & 127;
            float4 v = *(const float4*)(Xg + (size_t)m * DD + c4 * 4);
            float fv[4] = {v.x, v.y, v.z, v.w};
            #pragma unroll
            for (int j = 0; j < 4; ++j) {
                int d = c4 * 4 + j;
                Xt[d * 128 + (((m >> 3) ^ ((d >> 2) & 7)) << 3) + (m & 7)] = f2bf(fv[j]);
            }
        }
    }
    __syncthreads();

    u16* Og = Xagg + (size_t)batch * NN * DD;
    #pragma unroll
    for (int dh = 0; dh < 2; ++dh) {
        f32x16 acc1[2][2];
        #pragma unroll
        for (int fi = 0; fi < 2; ++fi)
            #pragma unroll
            for (int fd = 0; fd < 2; ++fd)
                #pragma unroll
                for (int r = 0; r < 16; ++r)
                    acc1[fi][fd][r] = 0.f;

        #pragma unroll
        for (int ksl = 0; ksl < 8; ++ksl) {
            const int kc = ksl * 2 + lh;
            bf16x8 af[2], bx[2];
            #pragma unroll
            for (int fi = 0; fi < 2; ++fi) {
                int i = wm * 64 + fi * 32 + l31;
                af[fi] = *(const bf16x8*)(Ms + i * 128 + ((kc ^ (i & 15)) << 3));
            }
            #pragma unroll
            for (int fd = 0; fd < 2; ++fd) {
                int d = dh * 256 + wn * 64 + fd * 32 + l31;
                bx[fd] = *(const bf16x8*)(Xt + d * 128 + ((kc ^ ((d >> 2) & 7)) << 3));
            }
            #pragma unroll
            for (int fi = 0; fi < 2; ++fi)
                #pragma unroll
                for (int fd = 0; fd < 2; ++fd)
                    acc1[fi][fd] = __builtin_amdgcn_mfma_f32_32x32x16_bf16(af[fi], bx[fd], acc1[fi][fd], 0, 0, 0);
        }

        #pragma unroll
        for (int fi = 0; fi < 2; ++fi)
            #pragma unroll
            for (int r = 0; r < 16; ++r) {
                int i = wm * 64 + fi * 32 + (r & 3) + 8 * (r >> 2) + 4 * lh;
                #pragma unroll
                for (int fd = 0; fd < 2; ++fd) {
                    int d = dh * 256 + wn * 64 + fd * 32 + l31;
                    Og[(size_t)i * DD + d] = f2bf(acc1[fi][fd][r]);
                }
            }
    }
}

// ---------------- out = sigmoid(LN( Xagg @ W^T + bias )) ----------------
// grid 1024 (M-tile 32), 256 thr = 4 waves; wave w -> h strip [128w, 128w+128).
// LDS = EXACTLY 64 KB: A-tile [32 m][512 k] bf16 resident (32K, staged once) +
// W slab [512 h][32 k] single-buffered (32K). 2x64=128 KB <= 160 -> 2 blocks/CU
// even with coarse LDS allocation granularity (R12's 72 KB ran 1 block/CU:
// OccupancyPercent 18.5 == known-1-block kernels). Stage latency covered by the
// co-resident block (m114). acc[4]=64 regs fits the observed 128-VGPR ceiling.
__global__ __launch_bounds__(256, 2) void gemm_ln_kernel(const u16* __restrict__ Xagg, const u16* __restrict__ Wb,
                                                         const float* __restrict__ bias, const float* __restrict__ lnw,
                                                         const float* __restrict__ lnb, float* __restrict__ out) {
    __shared__ __align__(16) char smem[65536];
    float* Pss = (float*)smem;                // overlay after K-loop: [4 w][32 row][2]
    float* musig = (float*)(smem + 1024);     // [32 row][2]

    const int t = threadIdx.x;
    const int lane = t & 63, w = t >> 6, l31 = lane & 31, lh = lane >> 5;
    const size_t rb = (size_t)blockIdx.x * 32;
    const u16* Xab = Xagg + rb * DD;

    float bias_v[4], lnw_v[4], lnb_v[4];
    #pragma unroll
    for (int fh = 0; fh < 4; ++fh) {
        int h = w * 128 + fh * 32 + l31;
        bias_v[fh] = bias[h];
        lnw_v[fh] = lnw[h];
        lnb_v[fh] = lnb[h];
    }

    // A-tile: linear LDS dest, inverse-swizzled source (c' = c ^ (m&15))
#define ASTAGE                                                                        \
    {                                                                                 \
        _Pragma("unroll")                                                             \
        for (int it_ = 0; it_ < 8; ++it_) {                                           \
            int q_ = it_ * 256 + t;                                                   \
            int m_ = q_ >> 6, cp_ = q_ & 63;                                          \
            gload16(Xab + (size_t)m_ * DD + ((cp_ ^ (m_ & 15)) * 8),                  \
                    (u16*)smem + q_ * 8);                                             \
        }                                                                             \
    }
    // W slab: same swizzle as R12 (c' = c ^ ((h>>1)&3)), single buffer @32768
#define WSTAGE(KS)                                                                    \
    {                                                                                 \
        u16* wl_ = (u16*)(smem + 32768);                                              \
        _Pragma("unroll")                                                             \
        for (int it_ = 0; it_ < 8; ++it_) {                                           \
            int q_ = it_ * 256 + t;                                                   \
            int h_ = q_ >> 2, cc_ = q_ & 3;                                           \
            gload16(Wb + (size_t)h_ * DD + (KS) * 32 + ((cc_ ^ ((h_ >> 1) & 3)) * 8), \
                    wl_ + q_ * 8);                                                    \
        }                                                                             \
    }

    f32x16 acc[4];
    #pragma unroll
    for (int fh = 0; fh < 4; ++fh)
        #pragma unroll
        for (int r = 0; r < 16; ++r)
            acc[fh][r] = 0.f;

    ASTAGE;
    WSTAGE(0);
    __syncthreads();

    for (int ks = 0; ks < 16; ++ks) {
        const u16* al = (const u16*)smem;
        const u16* wl = (const u16*)(smem + 32768);
        #pragma unroll
        for (int s2 = 0; s2 < 2; ++s2) {
            const int kc = s2 * 2 + lh;
            const int gc = ks * 4 + kc;           // global 16B k-chunk 0..63
            bf16x8 af = *(const bf16x8*)(al + (l31 * 64 + (gc ^ (l31 & 15))) * 8);
            bf16x8 bw[4];
            #pragma unroll
            for (int fh = 0; fh < 4; ++fh) {
                int h = w * 128 + fh * 32 + l31;
                bw[fh] = *(const bf16x8*)(wl + (h * 4 + (kc ^ ((h >> 1) & 3))) * 8);
            }
            #pragma unroll
            for (int fh = 0; fh < 4; ++fh)
                acc[fh] = __builtin_amdgcn_mfma_f32_32x32x16_bf16(af, bw[fh], acc[fh], 0, 0, 0);
        }
        if (ks < 15) {
            __syncthreads();      // all waves done reading W slab
            WSTAGE(ks + 1);       // overwrite single slab
            __syncthreads();      // drain gloads -> slab ready
        }
    }
#undef ASTAGE
#undef WSTAGE
    __syncthreads();   // slabs dead; overlay stats

    // bias + per-row stats over this wave's 128 h
    float rs[16], rss[16];
    #pragma unroll
    for (int r = 0; r < 16; ++r) {
        float s = 0.f, ss = 0.f;
        #pragma unroll
        for (int fh = 0; fh < 4; ++fh) {
            float a = acc[fh][r] + bias_v[fh];
            acc[fh][r] = a;
            s += a; ss += a * a;
        }
        rs[r] = s; rss[r] = ss;
    }
    #pragma unroll
    for (int msk = 1; msk <= 16; msk <<= 1)
        #pragma unroll
        for (int r = 0; r < 16; ++r) {
            rs[r] += __shfl_xor(rs[r], msk);
            rss[r] += __shfl_xor(rss[r], msk);
        }
    if (l31 == 0) {
        #pragma unroll
        for (int r = 0; r < 16; ++r) {
            int rl = (r & 3) + 8 * (r >> 2) + 4 * lh;
            float2 v; v.x = rs[r]; v.y = rss[r];
            *(float2*)(Pss + (w * 32 + rl) * 2) = v;
        }
    }
    __syncthreads();
    if (t < 32) {
        float s = 0.f, ss = 0.f;
        #pragma unroll
        for (int q = 0; q < 4; ++q) {
            float2 v = *(const float2*)(Pss + (q * 32 + t) * 2);
            s += v.x; ss += v.y;
        }
        float mean = s * (1.0f / 512.0f);
        float var = ss * (1.0f / 512.0f) - mean * mean;
        float2 mz; mz.x = mean; mz.y = rsqrtf(var + 1e-5f);
        *(float2*)(musig + t * 2) = mz;
    }
    __syncthreads();

    #pragma unroll
    for (int r = 0; r < 16; ++r) {
        int rl = (r & 3) + 8 * (r >> 2) + 4 * lh;
        float2 mz = *(const float2*)(musig + rl * 2);
        #pragma unroll
        for (int fh = 0; fh < 4; ++fh) {
            float xn = (acc[fh][r] - mz.x) * mz.y * lnw_v[fh] + lnb_v[fh];
            out[(rb + rl) * HH + w * 128 + fh * 32 + l31] = 1.0f / (1.0f + __expf(-xn));
        }
    }
}

extern "C" void kernel_launch(void* const* d_in, const int* in_sizes, int n_in,
                              void* d_out, int out_size, void* d_ws, size_t ws_size,
                              hipStream_t stream) {
    const float* X = (const float*)d_in[0];
    const float* A = (const float*)d_in[1];
    const float* W = (const float*)d_in[2];
    const float* bias = (const float*)d_in[3];
    const float* lnw = (const float*)d_in[4];
    const float* lnb = (const float*)d_in[5];
    float* out = (float*)d_out;

    u16* Xagg = (u16*)d_ws;                                  // B*N*D bf16 = 32 MB
    u16* Wb = (u16*)d_ws + (size_t)BB * NN * DD;             // H*D bf16 = 512 KB

    hipLaunchKernelGGL(wconv_kernel, dim3(256), dim3(256), 0, stream, W, Wb);
    hipLaunchKernelGGL(agg_kernel, dim3(256), dim3(512), 0, stream, X, A, Xagg);
    hipLaunchKernelGGL(gemm_ln_kernel, dim3(1024), dim3(256), 0, stream, Xagg, Wb, bias, lnw, lnb, out);
}

// Round 17
// 87.714 us; speedup vs baseline: 1.1167x; 1.0051x over previous
//
#include <hip/hip_runtime.h>
#include <cstdint>

#define BB 256
#define NN 128
#define DD 512
#define HH 512

typedef __attribute__((ext_vector_type(8))) short bf16x8;
typedef __attribute__((ext_vector_type(16))) float f32x16;
typedef unsigned short u16;

static __device__ __forceinline__ u16 f2bf(float f) {
    union { float f; uint32_t u; } v; v.f = f;
    uint32_t u = v.u;
    return (u16)((u + 0x7FFFu + ((u >> 16) & 1u)) >> 16);
}

static __device__ __forceinline__ void gload16(const u16* g, u16* l) {
    __builtin_amdgcn_global_load_lds((const __attribute__((address_space(1))) void*)g,
                                     (__attribute__((address_space(3))) void*)l, 16, 0, 0);
}

// ---------------- W fp32 -> bf16 TRANSPOSED chunk-major: Wt[kc][h][8] ----------------
// kc = d>>3 (64 16B-chunks per row). A wave's MFMA B-fragment (fixed kc, h = base+l31)
// is then 32 lanes x 16B CONTIGUOUS -> one coalesced dwordx4 per fragment from L2.
__global__ __launch_bounds__(256) void wconv_kernel(const float* __restrict__ W, u16* __restrict__ Wt) {
    int idx = (blockIdx.x * 256 + threadIdx.x) * 4;   // 4 floats of row h
    int h = idx >> 9, d = idx & 511;
    float4 v = *(const float4*)(W + idx);
    ushort4 o;
    o.x = f2bf(v.x); o.y = f2bf(v.y); o.z = f2bf(v.z); o.w = f2bf(v.w);
    *(ushort4*)(Wt + ((size_t)(d >> 3) * HH + h) * 8 + (d & 7)) = o;
}

// ---------------- Xagg = (I + A_norm) @ X -> HBM bf16  (R12-verified) ----------------
__global__ __launch_bounds__(512) void agg_kernel(const float* __restrict__ X, const float* __restrict__ A,
                                                  u16* __restrict__ Xagg) {
    __shared__ __align__(16) char smem[163840];
    u16* Ms = (u16*)smem;                 // [128 i][128 m], chunk c' = c ^ (i&15)
    u16* Xt = (u16*)(smem + 32768);       // [512 d][128 m], chunk c' = c ^ ((d>>2)&7)

    const int t = threadIdx.x;
    const int lane = t & 63, w = t >> 6, l31 = lane & 31, lh = lane >> 5;
    const int batch = blockIdx.x;
    const int wm = w >> 2, wn = w & 3;

    {
        const int row = t >> 2, seg = t & 3;
        const float* Ag = A + (size_t)batch * NN * NN + row * NN + seg * 32;
        float4 a[8];
        #pragma unroll
        for (int j = 0; j < 8; ++j) a[j] = *(const float4*)(Ag + j * 4);
        float s = 0.f;
        #pragma unroll
        for (int j = 0; j < 8; ++j) s += a[j].x + a[j].y + a[j].z + a[j].w;
        s += __shfl_xor(s, 1);
        s += __shfl_xor(s, 2);
        const float inv = 1.0f / (s + 1e-6f);
        #pragma unroll
        for (int c2 = 0; c2 < 4; ++c2) {
            u16 tmp[8];
            const float* pe = (const float*)&a[c2 * 2];
            #pragma unroll
            for (int e = 0; e < 8; ++e) {
                int m = seg * 32 + c2 * 8 + e;
                tmp[e] = f2bf(pe[e] * inv + (m == row ? 1.0f : 0.0f));
            }
            int c = seg * 4 + c2;
            *(uint4*)(Ms + row * 128 + ((c ^ (row & 15)) << 3)) = *(const uint4*)tmp;
        }
    }

    {
        const float* Xg = X + (size_t)batch * NN * DD;
        #pragma unroll
        for (int it = 0; it < 32; ++it) {
            int q = it * 512 + t;
            int m = q >> 7, c4 = q & 127;
            float4 v = *(const float4*)(Xg + (size_t)m * DD + c4 * 4);
            float fv[4] = {v.x, v.y, v.z, v.w};
            #pragma unroll
            for (int j = 0; j < 4; ++j) {
                int d = c4 * 4 + j;
                Xt[d * 128 + (((m >> 3) ^ ((d >> 2) & 7)) << 3) + (m & 7)] = f2bf(fv[j]);
            }
        }
    }
    __syncthreads();

    u16* Og = Xagg + (size_t)batch * NN * DD;
    #pragma unroll
    for (int dh = 0; dh < 2; ++dh) {
        f32x16 acc1[2][2];
        #pragma unroll
        for (int fi = 0; fi < 2; ++fi)
            #pragma unroll
            for (int fd = 0; fd < 2; ++fd)
                #pragma unroll
                for (int r = 0; r < 16; ++r)
                    acc1[fi][fd][r] = 0.f;

        #pragma unroll
        for (int ksl = 0; ksl < 8; ++ksl) {
            const int kc = ksl * 2 + lh;
            bf16x8 af[2], bx[2];
            #pragma unroll
            for (int fi = 0; fi < 2; ++fi) {
                int i = wm * 64 + fi * 32 + l31;
                af[fi] = *(const bf16x8*)(Ms + i * 128 + ((kc ^ (i & 15)) << 3));
            }
            #pragma unroll
            for (int fd = 0; fd < 2; ++fd) {
                int d = dh * 256 + wn * 64 + fd * 32 + l31;
                bx[fd] = *(const bf16x8*)(Xt + d * 128 + ((kc ^ ((d >> 2) & 7)) << 3));
            }
            #pragma unroll
            for (int fi = 0; fi < 2; ++fi)
                #pragma unroll
                for (int fd = 0; fd < 2; ++fd)
                    acc1[fi][fd] = __builtin_amdgcn_mfma_f32_32x32x16_bf16(af[fi], bx[fd], acc1[fi][fd], 0, 0, 0);
        }

        #pragma unroll
        for (int fi = 0; fi < 2; ++fi)
            #pragma unroll
            for (int r = 0; r < 16; ++r) {
                int i = wm * 64 + fi * 32 + (r & 3) + 8 * (r >> 2) + 4 * lh;
                #pragma unroll
                for (int fd = 0; fd < 2; ++fd) {
                    int d = dh * 256 + wn * 64 + fd * 32 + l31;
                    Og[(size_t)i * DD + d] = f2bf(acc1[fi][fd][r]);
                }
            }
    }
}

// ---------------- out = sigmoid(LN( Xagg @ W^T + bias )) ----------------
// grid 512 (M-tile 64), 512 thr = 8 waves; wave w -> h strip [64w, 64w+64).
// NO W staging, NO K-loop barriers: B-fragments read directly from transposed
// Wt (coalesced 512B/frag, L2-resident 512 KB). X tile [64m][512k] = 64 KB LDS
// staged once -> 2 blocks/CU, 16 waves/CU. acc[2][2]=64 VGPR under the 128 cap.
__global__ __launch_bounds__(512, 2) void gemm_ln_kernel(const u16* __restrict__ Xagg, const u16* __restrict__ Wt,
                                                         const float* __restrict__ bias, const float* __restrict__ lnw,
                                                         const float* __restrict__ lnb, float* __restrict__ out) {
    __shared__ __align__(16) char smem[65536];   // X tile; stats overlay after K-loop
    float* Pss = (float*)smem;                   // [8 w][64 row][2]
    float* musig = (float*)(smem + 4096);        // [64 row][2]

    const int t = threadIdx.x;
    const int lane = t & 63, w = t >> 6, l31 = lane & 31, lh = lane >> 5;
    const size_t rb = (size_t)blockIdx.x * 64;
    const u16* Xab = Xagg + rb * DD;

    float bias_v[2], lnw_v[2], lnb_v[2];
    #pragma unroll
    for (int fh = 0; fh < 2; ++fh) {
        int h = w * 64 + fh * 32 + l31;
        bias_v[fh] = bias[h];
        lnw_v[fh] = lnw[h];
        lnb_v[fh] = lnb[h];
    }

    // stage X tile: linear LDS dest, inverse-swizzled source (c' = c ^ (m&15)) — R16-verified
    #pragma unroll
    for (int it = 0; it < 8; ++it) {
        int q = it * 512 + t;
        int m = q >> 6, cp = q & 63;
        gload16(Xab + (size_t)m * DD + ((cp ^ (m & 15)) * 8), (u16*)smem + q * 8);
    }
    __syncthreads();   // drains gloads; X read-only hereafter

    f32x16 acc[2][2];   // [mi][fh]
    #pragma unroll
    for (int mi = 0; mi < 2; ++mi)
        #pragma unroll
        for (int fh = 0; fh < 2; ++fh)
            #pragma unroll
            for (int r = 0; r < 16; ++r)
                acc[mi][fh][r] = 0.f;

    const u16* al = (const u16*)smem;
    // K-loop: 32 16B-chunk steps (gc = 2*st + lh), fully unrolled, zero barriers
    #pragma unroll
    for (int st = 0; st < 32; ++st) {
        const int gc = st * 2 + lh;
        bf16x8 af[2], bw[2];
        #pragma unroll
        for (int mi = 0; mi < 2; ++mi) {
            int m = mi * 32 + l31;
            af[mi] = *(const bf16x8*)(al + (m * 64 + (gc ^ (m & 15))) * 8);
        }
        #pragma unroll
        for (int fh = 0; fh < 2; ++fh) {
            int h = w * 64 + fh * 32 + l31;
            bw[fh] = *(const bf16x8*)(Wt + ((size_t)gc * HH + h) * 8);
        }
        #pragma unroll
        for (int mi = 0; mi < 2; ++mi)
            #pragma unroll
            for (int fh = 0; fh < 2; ++fh)
                acc[mi][fh] = __builtin_amdgcn_mfma_f32_32x32x16_bf16(af[mi], bw[fh], acc[mi][fh], 0, 0, 0);
    }
    __syncthreads();   // X dead; overlay stats

    // bias + per-row partial stats over this wave's 64 h
    float rs[2][16], rss[2][16];
    #pragma unroll
    for (int mi = 0; mi < 2; ++mi)
        #pragma unroll
        for (int r = 0; r < 16; ++r) {
            float a0 = acc[mi][0][r] + bias_v[0];
            float a1 = acc[mi][1][r] + bias_v[1];
            acc[mi][0][r] = a0; acc[mi][1][r] = a1;
            rs[mi][r] = a0 + a1;
            rss[mi][r] = a0 * a0 + a1 * a1;
        }
    #pragma unroll
    for (int msk = 1; msk <= 16; msk <<= 1)
        #pragma unroll
        for (int mi = 0; mi < 2; ++mi)
            #pragma unroll
            for (int r = 0; r < 16; ++r) {
                rs[mi][r] += __shfl_xor(rs[mi][r], msk);
                rss[mi][r] += __shfl_xor(rss[mi][r], msk);
            }
    if (l31 == 0) {
        #pragma unroll
        for (int mi = 0; mi < 2; ++mi)
            #pragma unroll
            for (int r = 0; r < 16; ++r) {
                int rl = mi * 32 + (r & 3) + 8 * (r >> 2) + 4 * lh;
                float2 v; v.x = rs[mi][r]; v.y = rss[mi][r];
                *(float2*)(Pss + (w * 64 + rl) * 2) = v;
            }
    }
    __syncthreads();
    if (t < 64) {
        float s = 0.f, ss = 0.f;
        #pragma unroll
        for (int q = 0; q < 8; ++q) {
            float2 v = *(const float2*)(Pss + (q * 64 + t) * 2);
            s += v.x; ss += v.y;
        }
        float mean = s * (1.0f / 512.0f);
        float var = ss * (1.0f / 512.0f) - mean * mean;
        float2 mz; mz.x = mean; mz.y = rsqrtf(var + 1e-5f);
        *(float2*)(musig + t * 2) = mz;
    }
    __syncthreads();

    #pragma unroll
    for (int mi = 0; mi < 2; ++mi)
        #pragma unroll
        for (int r = 0; r < 16; ++r) {
            int rl = mi * 32 + (r & 3) + 8 * (r >> 2) + 4 * lh;
            float2 mz = *(const float2*)(musig + rl * 2);
            #pragma unroll
            for (int fh = 0; fh < 2; ++fh) {
                float xn = (acc[mi][fh][r] - mz.x) * mz.y * lnw_v[fh] + lnb_v[fh];
                out[(rb + rl) * HH + w * 64 + fh * 32 + l31] = 1.0f / (1.0f + __expf(-xn));
            }
        }
}

extern "C" void kernel_launch(void* const* d_in, const int* in_sizes, int n_in,
                              void* d_out, int out_size, void* d_ws, size_t ws_size,
                              hipStream_t stream) {
    const float* X = (const float*)d_in[0];
    const float* A = (const float*)d_in[1];
    const float* W = (const float*)d_in[2];
    const float* bias = (const float*)d_in[3];
    const float* lnw = (const float*)d_in[4];
    const float* lnb = (const float*)d_in[5];
    float* out = (float*)d_out;

    u16* Xagg = (u16*)d_ws;                                  // B*N*D bf16 = 32 MB
    u16* Wt = (u16*)d_ws + (size_t)BB * NN * DD;             // transposed W bf16 = 512 KB

    hipLaunchKernelGGL(wconv_kernel, dim3(256), dim3(256), 0, stream, W, Wt);
    hipLaunchKernelGGL(agg_kernel, dim3(256), dim3(512), 0, stream, X, A, Xagg);
    hipLaunchKernelGGL(gemm_ln_kernel, dim3(512), dim3(512), 0, stream, Xagg, Wt, bias, lnw, lnb, out);
}